// Round 4
// baseline (443.603 us; speedup 1.0000x reference)
//
#include <hip/hip_runtime.h>

// Conv2D_80796924772741: grouped (per-F) 3x3x1 valid correlation + int8 requantize.
// Harness protocol: int8 tensors are widened to int32 on both input AND output.
//   x: int32 [64,514,514,4], w: int32 [64,3,3,1], b: int32 [64]
//   out: int32 [64,512,512,4]  (quantized int8 values stored as int32)
// Quant: reduced_mantissa = (1305500416 + (1<<15)) >> 16 = 19920 = 16*1245
//        total_shifts = 22.  (acc*19920 + 2^21) >> 22  ==  (acc*1245 + 2^17) >> 18
//        (exact: *16 then >>22 == >>18; acc*1245 <= ~1.82e8 fits int32)
//        then + OUT_ZP(-5), clip [-128,127]
// All MACs via __mul24 (v_mad_i32_i24, full-rate): |x|,|w| <= 128 so products
// fit 24-bit; accumulator rides in the mad's 32-bit addend. Avoids quarter-rate
// v_mul_lo_u32 and all 64-bit math.

#define NF 64
#define HH 514
#define WW 514
#define OH 512
#define OW 512
#define RB 8   // output rows per thread: reads RB+2 rows -> 1.25x fetch amp

typedef int iv4 __attribute__((ext_vector_type(4)));  // native vec: works with
                                                      // __builtin_nontemporal_store

__device__ __forceinline__ int quantize(int acc) {
    int r = (__mul24(acc, 1245) + (1 << 17)) >> 18;   // arithmetic shift
    r += -5;                                          // OUT_ZP
    return max(-128, min(127, r));
}

__global__ __launch_bounds__(256) void conv2d_q_kernel(const int* __restrict__ x,
                                                       const int* __restrict__ w,
                                                       const int* __restrict__ b,
                                                       int* __restrict__ out) {
    const int f   = blockIdx.z;
    const int oh0 = blockIdx.y * RB;
    const int ow  = blockIdx.x * 256 + threadIdx.x;

    // Wave-uniform weights + bias -> scalar loads.
    int wgt[9];
#pragma unroll
    for (int k = 0; k < 9; ++k) wgt[k] = w[f * 9 + k];
    const int bias = b[f];

    const iv4* __restrict__ xv = reinterpret_cast<const iv4*>(x);
    iv4* __restrict__ ov = reinterpret_cast<iv4*>(out);

    int acc[RB][4];
#pragma unroll
    for (int r = 0; r < RB; ++r)
#pragma unroll
        for (int c = 0; c < 4; ++c) acc[r][c] = bias;

    const int xbase = (f * HH + oh0) * WW + ow;   // iv4-granular index

    // Stream RB+2 input rows; row h feeds output rows r = h-2..h (weight row m = h-r).
#pragma unroll
    for (int h = 0; h < RB + 2; ++h) {
        const iv4 t0 = xv[xbase + h * WW + 0];
        const iv4 t1 = xv[xbase + h * WW + 1];
        const iv4 t2 = xv[xbase + h * WW + 2];
#pragma unroll
        for (int r = 0; r < RB; ++r) {
            const int m = h - r;
            if (m >= 0 && m < 3) {
                const int c0 = wgt[m * 3 + 0];
                const int c1 = wgt[m * 3 + 1];
                const int c2 = wgt[m * 3 + 2];
#pragma unroll
                for (int c = 0; c < 4; ++c)
                    acc[r][c] += __mul24(t0[c], c0) + __mul24(t1[c], c1) + __mul24(t2[c], c2);
            }
        }
    }

    const int obase = (f * OH + oh0) * OW + ow;
#pragma unroll
    for (int r = 0; r < RB; ++r) {
        iv4 o;
#pragma unroll
        for (int c = 0; c < 4; ++c) o[c] = quantize(acc[r][c]);
        __builtin_nontemporal_store(o, &ov[obase + r * OW]);  // streamed, no reuse
    }
}

extern "C" void kernel_launch(void* const* d_in, const int* in_sizes, int n_in,
                              void* d_out, int out_size, void* d_ws, size_t ws_size,
                              hipStream_t stream) {
    const int* x = (const int*)d_in[0];
    const int* w = (const int*)d_in[1];
    const int* b = (const int*)d_in[2];
    int* out = (int*)d_out;

    dim3 grid(OW / 256, OH / RB, NF);   // (2, 64, 64)
    dim3 block(256, 1, 1);
    conv2d_q_kernel<<<grid, block, 0, stream>>>(x, w, b, out);
}